// Round 1
// baseline (214.283 us; speedup 1.0000x reference)
//
#include <hip/hip_runtime.h>
#include <math.h>

#define BATCH 2048
#define LATENT 64
#define LOG_2PI 1.8378770664093453f
#define BETA_M1 5.0f
#define LN2 0.69314718055994530942f
// C2 = -0.5 * log2(e)
#define C2 (-0.72134752044448170368f)

// ws layout (float offsets):
//   Vt   [128][2048]  Vt[2l][j]=C2*inv, Vt[2l+1][j]=C2*m*inv
//   Tce  [64][2048]   Tce[l][j]=C2*(m^2*inv+lv+LOG2PI)
//   Up   [128][2048]  Up[2l][i]=z^2, Up[2l+1][i]=-2z
//   CE   [2048], KLP [2048]
//   RMP/RSP [8][2048] row-LSE partials (log2 domain)
//   PART [16]         PART[0]=tc sum, PART[1]=kl sum, PART[2]=ticket counter
//   SM   [64][2048]   fp32 per-(l,i) exp sums (atomic-accumulated)
#define OFF_VT   0
#define OFF_TCE  (128*BATCH)
#define OFF_UP   (OFF_TCE + 64*BATCH)
#define OFF_CE   (OFF_UP + 128*BATCH)
#define OFF_KLP  (OFF_CE + BATCH)
#define OFF_RMP  (OFF_KLP + BATCH)
#define OFF_RSP  (OFF_RMP + 8*BATCH)
#define OFF_PART (OFF_RSP + 8*BATCH)
#define OFF_SM   (OFF_PART + 16)

// Precompute: grid 128 x 256, each block transposes 16 j x 64 l.
// Also zeroes SM (131072 floats) and PART.
__global__ __launch_bounds__(256) void precompute_kernel(const float* __restrict__ z,
                                                         const float* __restrict__ zm,
                                                         const float* __restrict__ zlv,
                                                         float* __restrict__ ws) {
    __shared__ float Tz[16][65], Tm[16][65], Tlv[16][65];
    __shared__ float CEp[16][16], KLp[16][16];
    int t = threadIdx.x, lane = t & 63, w = t >> 6;
    int j0 = blockIdx.x * 16;

    #pragma unroll
    for (int p = 0; p < 4; ++p) {
        int jr = p * 4 + w;
        int idx = (j0 + jr) * LATENT + lane;
        Tz[jr][lane]  = z[idx];
        Tm[jr][lane]  = zm[idx];
        Tlv[jr][lane] = zlv[idx];
    }
    // zero SM accumulator and PART
    {
        int gid = blockIdx.x * 256 + t;
        #pragma unroll
        for (int k = 0; k < 4; ++k) ws[OFF_SM + gid + 32768 * k] = 0.0f;
    }
    if (blockIdx.x == 0 && t < 16) ws[OFF_PART + t] = 0.0f;
    __syncthreads();

    int jl = t & 15, lg = t >> 4;
    int j = j0 + jl;
    float ce_acc = 0.0f, kl_acc = 0.0f;
    #pragma unroll
    for (int q = 0; q < 4; ++q) {
        int l = q * 16 + lg;
        float zv = Tz[jl][l];
        float m  = Tm[jl][l];
        float lv = Tlv[jl][l];
        float iv  = __expf(-lv);
        float civ = C2 * iv;
        float miv = m * iv;
        float cmv = C2 * miv;
        float cev = C2 * fmaf(m, miv, lv + LOG_2PI);
        ws[OFF_VT  + (2*l)   * BATCH + j] = civ;
        ws[OFF_VT  + (2*l+1) * BATCH + j] = cmv;
        ws[OFF_TCE + l       * BATCH + j] = cev;
        ws[OFF_UP  + (2*l)   * BATCH + j] = zv * zv;
        ws[OFF_UP  + (2*l+1) * BATCH + j] = -2.0f * zv;
        ce_acc += cev;
        kl_acc += fmaf(m, m, __expf(lv)) - lv - 1.0f;
    }
    CEp[lg][jl] = ce_acc;
    KLp[lg][jl] = kl_acc;
    __syncthreads();
    if (t < 16) {
        float ce = 0.0f, kl = 0.0f;
        #pragma unroll
        for (int g = 0; g < 16; ++g) { ce += CEp[g][t]; kl += KLp[g][t]; }
        ws[OFF_CE  + j0 + t] = ce;
        ws[OFF_KLP + j0 + t] = kl;
    }
}

// ---- unified main: 2048 identical blocks, each does one dim sub-task and
// ---- one row sub-task; order staggered by bit 8 of blockIdx so every SIMD
// ---- hosts a mix of exp-heavy (trans pipe) and fma-heavy (VALU pipe) waves.

__device__ __forceinline__ void dim_part(float* __restrict__ ws, int bx, int t) {
    // (l, jc) = (bx>>5, bx&31): 1 latent dim, 64-j chunk, all 2048 i.
    int l = bx >> 5, jc = bx & 31;
    const float* __restrict__ up0 = ws + OFF_UP + (2*l)   * BATCH;
    const float* __restrict__ up1 = ws + OFF_UP + (2*l+1) * BATCH;
    float z2[8], n2[8];
    #pragma unroll
    for (int k = 0; k < 8; ++k) {
        z2[k] = up0[t + 256*k];
        n2[k] = up1[t + 256*k];
    }
    const float* __restrict__ pc = ws + OFF_VT  + (2*l)   * BATCH + jc * 64;
    const float* __restrict__ pm = ws + OFF_VT  + (2*l+1) * BATCH + jc * 64;
    const float* __restrict__ pe = ws + OFF_TCE + l       * BATCH + jc * 64;

    float s[8];
    #pragma unroll
    for (int k = 0; k < 8; ++k) s[k] = 0.0f;

    #pragma unroll 1
    for (int jj = 0; jj < 64; jj += 8) {
        #pragma unroll
        for (int u = 0; u < 8; ++u) {
            float cc = pc[jj + u];
            float mm = pm[jj + u];
            float ee = pe[jj + u];
            #pragma unroll
            for (int k = 0; k < 8; ++k)
                s[k] += __builtin_amdgcn_exp2f(fmaf(z2[k], cc, fmaf(n2[k], mm, ee)));
        }
    }
    #pragma unroll
    for (int k = 0; k < 8; ++k)
        atomicAdd(&ws[OFF_SM + l * BATCH + t + 256*k], s[k]);
}

__device__ __forceinline__ void row_part(float* __restrict__ ws, int bx, int t,
                                         float* __restrict__ Ups,
                                         float (*RMs)[4], float (*RSs)[4]) {
    // (ig, jq) = (bx>>3, bx&7): 8 i rows, 256-j chunk, all 64 l.
    int ig = bx >> 3, jq = bx & 7;
    int i0 = ig * 8;
    int j  = jq * 256 + t;

    // stage Up[*][i0..i0+7] (128 rows x 8 floats = 4KB) into LDS
    #pragma unroll
    for (int p = 0; p < 4; ++p) {
        int f = t + 256 * p;
        Ups[f] = ws[OFF_UP + (f >> 3) * BATCH + i0 + (f & 7)];
    }
    __syncthreads();

    float r[8];
    #pragma unroll
    for (int i = 0; i < 8; ++i) r[i] = 0.0f;

    const float* __restrict__ Vt = ws + OFF_VT;
    for (int l = 0; l < LATENT; ++l) {
        float v0 = Vt[(2*l)   * BATCH + j];
        float v1 = Vt[(2*l+1) * BATCH + j];
        const float* __restrict__ ua = Ups + (2*l)   * 8;
        const float* __restrict__ ub = Ups + (2*l+1) * 8;
        #pragma unroll
        for (int i = 0; i < 8; ++i)
            r[i] = fmaf(ua[i], v0, fmaf(ub[i], v1, r[i]));
    }

    float ce = ws[OFF_CE + j];
    int lane = t & 63, w = t >> 6;
    #pragma unroll
    for (int i = 0; i < 8; ++i) {
        float M = r[i] + ce;
        float S = 1.0f;
        #pragma unroll
        for (int off = 32; off > 0; off >>= 1) {
            float Mo = __shfl_xor(M, off, 64);
            float So = __shfl_xor(S, off, 64);
            float mn = fmaxf(M, Mo);
            S = S * __builtin_amdgcn_exp2f(M - mn) + So * __builtin_amdgcn_exp2f(Mo - mn);
            M = mn;
        }
        if (lane == 0) { RMs[i][w] = M; RSs[i][w] = S; }
    }
    __syncthreads();
    if (t < 8) {
        float M = RMs[t][0], S = RSs[t][0];
        #pragma unroll
        for (int w2 = 1; w2 < 4; ++w2) {
            float Mo = RMs[t][w2], So = RSs[t][w2];
            float mn = fmaxf(M, Mo);
            S = S * __builtin_amdgcn_exp2f(M - mn) + So * __builtin_amdgcn_exp2f(Mo - mn);
            M = mn;
        }
        ws[OFF_RMP + jq * BATCH + i0 + t] = M;
        ws[OFF_RSP + jq * BATCH + i0 + t] = S;
    }
}

__global__ __launch_bounds__(256, 8) void main_kernel(float* __restrict__ ws) {
    __shared__ float Ups[1024];
    __shared__ float RMs[8][4], RSs[8][4];
    int bx = blockIdx.x, t = threadIdx.x;
    // Co-resident blocks on a CU are spaced 256 apart -> bit 8 alternates.
    if (((bx >> 8) & 1) == 0) {
        dim_part(ws, bx, t);
        row_part(ws, bx, t, Ups, RMs, RSs);
    } else {
        row_part(ws, bx, t, Ups, RMs, RSs);
        dim_part(ws, bx, t);
    }
}

// Finalize: tc = sum_i lqz_i - sum_{l,i} log2(SM[l][i]); kl = sum_i KLP[i].
// Last block (atomic ticket) assembles the scalar output.
__global__ __launch_bounds__(256) void finalize_kernel(float* __restrict__ ws,
                                                       float* __restrict__ out) {
    __shared__ float s_tc[256];
    __shared__ float s_kl[256];
    int t = threadIdx.x;
    int gid = blockIdx.x * 256 + t;

    float acc = 0.0f, kl = 0.0f;
    #pragma unroll
    for (int k = 0; k < 4; ++k) {
        float s = ws[OFF_SM + gid + 32768 * k];
        acc -= __builtin_amdgcn_logf(s);   // log2; scaled by LN2 at the end
    }

    if (gid < BATCH) {
        int i = gid;
        float M = ws[OFF_RMP + i];
        float S = ws[OFF_RSP + i];
        #pragma unroll
        for (int q = 1; q < 8; ++q) {
            float Mo = ws[OFF_RMP + q * BATCH + i];
            float So = ws[OFF_RSP + q * BATCH + i];
            float mn = fmaxf(M, Mo);
            S = S * __builtin_amdgcn_exp2f(M - mn) + So * __builtin_amdgcn_exp2f(Mo - mn);
            M = mn;
        }
        acc += M + __builtin_amdgcn_logf(S);
        kl = ws[OFF_KLP + i];
    }

    s_tc[t] = acc; s_kl[t] = kl;
    __syncthreads();
    for (int s2 = 128; s2 > 0; s2 >>= 1) {
        if (t < s2) { s_tc[t] += s_tc[t + s2]; s_kl[t] += s_kl[t + s2]; }
        __syncthreads();
    }
    if (t == 0) {
        atomicAdd(&ws[OFF_PART + 0], s_tc[0]);
        atomicAdd(&ws[OFF_PART + 1], s_kl[0]);
        __threadfence();
        unsigned int old = atomicAdd((unsigned int*)(ws + OFF_PART + 2), 1u);
        if (old == 127u) {
            float tc  = atomicAdd(&ws[OFF_PART + 0], 0.0f);
            float kl2 = atomicAdd(&ws[OFF_PART + 1], 0.0f);
            out[0] = BETA_M1 * (LN2 * tc / (float)BATCH) + 0.5f * (kl2 / (float)BATCH);
        }
    }
}

extern "C" void kernel_launch(void* const* d_in, const int* in_sizes, int n_in,
                              void* d_out, int out_size, void* d_ws, size_t ws_size,
                              hipStream_t stream) {
    const float* z        = (const float*)d_in[0];
    const float* z_mean   = (const float*)d_in[1];
    const float* z_logvar = (const float*)d_in[2];
    float* out = (float*)d_out;
    float* ws  = (float*)d_ws;

    precompute_kernel<<<128, 256, 0, stream>>>(z, z_mean, z_logvar, ws);
    main_kernel<<<2048, 256, 0, stream>>>(ws);
    finalize_kernel<<<128, 256, 0, stream>>>(ws, out);
}

// Round 2
// 169.881 us; speedup vs baseline: 1.2614x; 1.2614x over previous
//
#include <hip/hip_runtime.h>
#include <math.h>

#define BATCH 2048
#define LATENT 64
#define LOG_2PI 1.8378770664093453f
#define BETA_M1 5.0f
#define LN2 0.69314718055994530942f
// C2 = -0.5 * log2(e)
#define C2 (-0.72134752044448170368f)

// ws layout (float offsets):
//   Vt   [128][2048]  Vt[2l][j]=C2*inv, Vt[2l+1][j]=C2*m*inv
//   Tce  [64][2048]   Tce[l][j]=C2*(m^2*inv+lv+LOG2PI)
//   Up   [128][2048]  Up[2l][i]=z^2, Up[2l+1][i]=-2z
//   CE   [2048], KLP [2048]
//   RMP/RSP [8][2048] row-LSE partials (log2 domain)
//   PART [16]         PART[0]=tc sum, PART[1]=kl sum, PART[2]=ticket counter
//   SM   [64][2048]   fp32 per-(l,i) exp sums (plain stores, one writer per elem)
#define OFF_VT   0
#define OFF_TCE  (128*BATCH)
#define OFF_UP   (OFF_TCE + 64*BATCH)
#define OFF_CE   (OFF_UP + 128*BATCH)
#define OFF_KLP  (OFF_CE + BATCH)
#define OFF_RMP  (OFF_KLP + BATCH)
#define OFF_RSP  (OFF_RMP + 8*BATCH)
#define OFF_PART (OFF_RSP + 8*BATCH)
#define OFF_SM   (OFF_PART + 16)

// Precompute: grid 128 x 256, each block transposes 16 j x 64 l.
__global__ __launch_bounds__(256) void precompute_kernel(const float* __restrict__ z,
                                                         const float* __restrict__ zm,
                                                         const float* __restrict__ zlv,
                                                         float* __restrict__ ws) {
    __shared__ float Tz[16][65], Tm[16][65], Tlv[16][65];
    __shared__ float CEp[16][16], KLp[16][16];
    int t = threadIdx.x, lane = t & 63, w = t >> 6;
    int j0 = blockIdx.x * 16;

    #pragma unroll
    for (int p = 0; p < 4; ++p) {
        int jr = p * 4 + w;
        int idx = (j0 + jr) * LATENT + lane;
        Tz[jr][lane]  = z[idx];
        Tm[jr][lane]  = zm[idx];
        Tlv[jr][lane] = zlv[idx];
    }
    if (blockIdx.x == 0 && t < 16) ws[OFF_PART + t] = 0.0f;
    __syncthreads();

    int jl = t & 15, lg = t >> 4;
    int j = j0 + jl;
    float ce_acc = 0.0f, kl_acc = 0.0f;
    #pragma unroll
    for (int q = 0; q < 4; ++q) {
        int l = q * 16 + lg;
        float zv = Tz[jl][l];
        float m  = Tm[jl][l];
        float lv = Tlv[jl][l];
        float iv  = __expf(-lv);
        float civ = C2 * iv;
        float miv = m * iv;
        float cmv = C2 * miv;
        float cev = C2 * fmaf(m, miv, lv + LOG_2PI);
        ws[OFF_VT  + (2*l)   * BATCH + j] = civ;
        ws[OFF_VT  + (2*l+1) * BATCH + j] = cmv;
        ws[OFF_TCE + l       * BATCH + j] = cev;
        ws[OFF_UP  + (2*l)   * BATCH + j] = zv * zv;
        ws[OFF_UP  + (2*l+1) * BATCH + j] = -2.0f * zv;
        ce_acc += cev;
        kl_acc += fmaf(m, m, __expf(lv)) - lv - 1.0f;
    }
    CEp[lg][jl] = ce_acc;
    KLp[lg][jl] = kl_acc;
    __syncthreads();
    if (t < 16) {
        float ce = 0.0f, kl = 0.0f;
        #pragma unroll
        for (int g = 0; g < 16; ++g) { ce += CEp[g][t]; kl += KLp[g][t]; }
        ws[OFF_CE  + j0 + t] = ce;
        ws[OFF_KLP + j0 + t] = kl;
    }
}

// ---- unified main: 2048 identical blocks, each does one dim sub-task and
// ---- one row sub-task; order staggered by bit 8 of blockIdx so every SIMD
// ---- hosts a mix of exp-heavy (trans pipe) and fma-heavy (VALU pipe) waves.

// dim: (l, ic) = (bx>>5, bx&31). Block owns SM[l][ic*64 .. +64) -- the FULL
// j-sum, so plain stores (no atomics). Threads: 8 i-groups x 32 j-stripes.
__device__ __forceinline__ void dim_part(float* __restrict__ ws, int bx, int t,
                                         float (*Dred)[64]) {
    int l = bx >> 5, ic = bx & 31;
    int i0 = ic * 64;
    int ig = t & 7, js = t >> 3;
    int ib = i0 + ig * 8;

    const float* __restrict__ up0 = ws + OFF_UP + (2*l)   * BATCH + ib;
    const float* __restrict__ up1 = ws + OFF_UP + (2*l+1) * BATCH + ib;
    float4 za = *(const float4*)(up0);
    float4 zb = *(const float4*)(up0 + 4);
    float4 na = *(const float4*)(up1);
    float4 nb = *(const float4*)(up1 + 4);
    float z2[8] = {za.x, za.y, za.z, za.w, zb.x, zb.y, zb.z, zb.w};
    float n2[8] = {na.x, na.y, na.z, na.w, nb.x, nb.y, nb.z, nb.w};

    const float4* __restrict__ pc4 = (const float4*)(ws + OFF_VT  + (2*l)   * BATCH + js * 64);
    const float4* __restrict__ pm4 = (const float4*)(ws + OFF_VT  + (2*l+1) * BATCH + js * 64);
    const float4* __restrict__ pe4 = (const float4*)(ws + OFF_TCE + l       * BATCH + js * 64);

    float s[8];
    #pragma unroll
    for (int k = 0; k < 8; ++k) s[k] = 0.0f;

    #pragma unroll 4
    for (int q = 0; q < 16; ++q) {
        float4 cc = pc4[q], mm = pm4[q], ee = pe4[q];
        #pragma unroll
        for (int k = 0; k < 8; ++k) {
            s[k] += __builtin_amdgcn_exp2f(fmaf(z2[k], cc.x, fmaf(n2[k], mm.x, ee.x)));
            s[k] += __builtin_amdgcn_exp2f(fmaf(z2[k], cc.y, fmaf(n2[k], mm.y, ee.y)));
            s[k] += __builtin_amdgcn_exp2f(fmaf(z2[k], cc.z, fmaf(n2[k], mm.z, ee.z)));
            s[k] += __builtin_amdgcn_exp2f(fmaf(z2[k], cc.w, fmaf(n2[k], mm.w, ee.w)));
        }
    }

    // reduce the 8 j-stripes within each wave (stripe bits are t[5:3])
    #pragma unroll
    for (int off = 8; off < 64; off <<= 1) {
        #pragma unroll
        for (int k = 0; k < 8; ++k)
            s[k] += __shfl_xor(s[k], off, 64);
    }
    int lane = t & 63, w = t >> 6;
    if (lane < 8) {
        #pragma unroll
        for (int k = 0; k < 8; ++k) Dred[w][lane * 8 + k] = s[k];
    }
    __syncthreads();
    if (t < 64) {
        float v = Dred[0][t] + Dred[1][t] + Dred[2][t] + Dred[3][t];
        ws[OFF_SM + l * BATCH + i0 + t] = v;
    }
    __syncthreads();
}

__device__ __forceinline__ void row_part(float* __restrict__ ws, int bx, int t,
                                         float* __restrict__ Ups,
                                         float (*RMs)[4], float (*RSs)[4]) {
    // (ig, jq) = (bx>>3, bx&7): 8 i rows, 256-j chunk, all 64 l.
    int ig = bx >> 3, jq = bx & 7;
    int i0 = ig * 8;
    int j  = jq * 256 + t;

    // stage Up[*][i0..i0+7] (128 rows x 8 floats = 4KB) into LDS
    #pragma unroll
    for (int p = 0; p < 4; ++p) {
        int f = t + 256 * p;
        Ups[f] = ws[OFF_UP + (f >> 3) * BATCH + i0 + (f & 7)];
    }
    __syncthreads();

    float r[8];
    #pragma unroll
    for (int i = 0; i < 8; ++i) r[i] = 0.0f;

    const float* __restrict__ Vt = ws + OFF_VT;
    for (int l = 0; l < LATENT; ++l) {
        float v0 = Vt[(2*l)   * BATCH + j];
        float v1 = Vt[(2*l+1) * BATCH + j];
        const float* __restrict__ ua = Ups + (2*l)   * 8;
        const float* __restrict__ ub = Ups + (2*l+1) * 8;
        #pragma unroll
        for (int i = 0; i < 8; ++i)
            r[i] = fmaf(ua[i], v0, fmaf(ub[i], v1, r[i]));
    }

    float ce = ws[OFF_CE + j];
    int lane = t & 63, w = t >> 6;
    #pragma unroll
    for (int i = 0; i < 8; ++i) {
        float M = r[i] + ce;
        float S = 1.0f;
        #pragma unroll
        for (int off = 32; off > 0; off >>= 1) {
            float Mo = __shfl_xor(M, off, 64);
            float So = __shfl_xor(S, off, 64);
            float mn = fmaxf(M, Mo);
            S = S * __builtin_amdgcn_exp2f(M - mn) + So * __builtin_amdgcn_exp2f(Mo - mn);
            M = mn;
        }
        if (lane == 0) { RMs[i][w] = M; RSs[i][w] = S; }
    }
    __syncthreads();
    if (t < 8) {
        float M = RMs[t][0], S = RSs[t][0];
        #pragma unroll
        for (int w2 = 1; w2 < 4; ++w2) {
            float Mo = RMs[t][w2], So = RSs[t][w2];
            float mn = fmaxf(M, Mo);
            S = S * __builtin_amdgcn_exp2f(M - mn) + So * __builtin_amdgcn_exp2f(Mo - mn);
            M = mn;
        }
        ws[OFF_RMP + jq * BATCH + i0 + t] = M;
        ws[OFF_RSP + jq * BATCH + i0 + t] = S;
    }
    __syncthreads();
}

__global__ __launch_bounds__(256, 8) void main_kernel(float* __restrict__ ws) {
    __shared__ float Ups[1024];
    __shared__ float Dred[4][64];
    __shared__ float RMs[8][4], RSs[8][4];
    int bx = blockIdx.x, t = threadIdx.x;
    // Co-resident blocks on a CU are spaced 256 apart -> bit 8 alternates.
    if (((bx >> 8) & 1) == 0) {
        dim_part(ws, bx, t, Dred);
        row_part(ws, bx, t, Ups, RMs, RSs);
    } else {
        row_part(ws, bx, t, Ups, RMs, RSs);
        dim_part(ws, bx, t, Dred);
    }
}

// Finalize: tc = sum_i lqz_i - sum_{l,i} log2(SM[l][i]); kl = sum_i KLP[i].
// Last block (atomic ticket) assembles the scalar output.
__global__ __launch_bounds__(256) void finalize_kernel(float* __restrict__ ws,
                                                       float* __restrict__ out) {
    __shared__ float s_tc[256];
    __shared__ float s_kl[256];
    int t = threadIdx.x;
    int gid = blockIdx.x * 256 + t;

    float acc = 0.0f, kl = 0.0f;
    #pragma unroll
    for (int k = 0; k < 4; ++k) {
        float s = ws[OFF_SM + gid + 32768 * k];
        acc -= __builtin_amdgcn_logf(s);   // log2; scaled by LN2 at the end
    }

    if (gid < BATCH) {
        int i = gid;
        float M = ws[OFF_RMP + i];
        float S = ws[OFF_RSP + i];
        #pragma unroll
        for (int q = 1; q < 8; ++q) {
            float Mo = ws[OFF_RMP + q * BATCH + i];
            float So = ws[OFF_RSP + q * BATCH + i];
            float mn = fmaxf(M, Mo);
            S = S * __builtin_amdgcn_exp2f(M - mn) + So * __builtin_amdgcn_exp2f(Mo - mn);
            M = mn;
        }
        acc += M + __builtin_amdgcn_logf(S);
        kl = ws[OFF_KLP + i];
    }

    s_tc[t] = acc; s_kl[t] = kl;
    __syncthreads();
    for (int s2 = 128; s2 > 0; s2 >>= 1) {
        if (t < s2) { s_tc[t] += s_tc[t + s2]; s_kl[t] += s_kl[t + s2]; }
        __syncthreads();
    }
    if (t == 0) {
        atomicAdd(&ws[OFF_PART + 0], s_tc[0]);
        atomicAdd(&ws[OFF_PART + 1], s_kl[0]);
        __threadfence();
        unsigned int old = atomicAdd((unsigned int*)(ws + OFF_PART + 2), 1u);
        if (old == 127u) {
            float tc  = atomicAdd(&ws[OFF_PART + 0], 0.0f);
            float kl2 = atomicAdd(&ws[OFF_PART + 1], 0.0f);
            out[0] = BETA_M1 * (LN2 * tc / (float)BATCH) + 0.5f * (kl2 / (float)BATCH);
        }
    }
}

extern "C" void kernel_launch(void* const* d_in, const int* in_sizes, int n_in,
                              void* d_out, int out_size, void* d_ws, size_t ws_size,
                              hipStream_t stream) {
    const float* z        = (const float*)d_in[0];
    const float* z_mean   = (const float*)d_in[1];
    const float* z_logvar = (const float*)d_in[2];
    float* out = (float*)d_out;
    float* ws  = (float*)d_ws;

    precompute_kernel<<<128, 256, 0, stream>>>(z, z_mean, z_logvar, ws);
    main_kernel<<<2048, 256, 0, stream>>>(ws);
    finalize_kernel<<<128, 256, 0, stream>>>(ws, out);
}